// Round 5
// baseline (232.530 us; speedup 1.0000x reference)
//
#include <hip/hip_runtime.h>
#include <hip/hip_bf16.h>

#define B_   4
#define TQ_  2048
#define TKV_ 2048
#define DM_  1024
#define H_   16
#define DH_  64

// 1/sqrt(DK) * log2(e), folded into Wq/bq so attention exp2 needs no scaling
#define SC_FOLD 0.18033688011112042f

using f32x4  = __attribute__((ext_vector_type(4))) float;
using f32x16 = __attribute__((ext_vector_type(16))) float;
using s16x8  = __attribute__((ext_vector_type(8))) short;

static __device__ __forceinline__ unsigned short f2bf(float f) {
  union { float f; unsigned int u; } v; v.f = f;
  unsigned int r = v.u + 0x7FFFu + ((v.u >> 16) & 1u);
  return (unsigned short)(r >> 16);
}
// packed f32 pair -> 2xbf16 (RNE) in one instruction
static __device__ __forceinline__ unsigned int pk2(float a, float b) {
  unsigned int r;
  asm("v_cvt_pk_bf16_f32 %0, %1, %2" : "=v"(r) : "v"(a), "v"(b));
  return r;
}

// async global->LDS, 16B per lane; LDS dest is wave-uniform base + lane*16
#define GL16(g, l)                                                          \
  __builtin_amdgcn_global_load_lds(                                         \
      (const __attribute__((address_space(1))) unsigned int*)(g),           \
      (__attribute__((address_space(3))) unsigned int*)(l), 16, 0, 0)

// ---------------- transpose + cast + scale: W[K][N] f32 -> WT[N][K] bf16 ----------------
__global__ __launch_bounds__(256) void k_transpose_cast(
    const float* __restrict__ W, unsigned short* __restrict__ WT, int K, int N,
    float scale) {
  __shared__ float t[64][65];
  int n0 = blockIdx.x * 64, k0 = blockIdx.y * 64;
  int tx = threadIdx.x & 63, ty = threadIdx.x >> 6;
#pragma unroll
  for (int i = 0; i < 64; i += 4)
    t[ty + i][tx] = W[(size_t)(k0 + ty + i) * N + n0 + tx];
  __syncthreads();
#pragma unroll
  for (int i = 0; i < 64; i += 4)
    WT[(size_t)(n0 + ty + i) * K + k0 + tx] = f2bf(t[tx][ty + i] * scale);
}

// ---------------- elementwise cast f32 -> bf16 ----------------
__global__ __launch_bounds__(256) void k_cast_bf16(
    const float* __restrict__ in, unsigned short* __restrict__ out, int n4) {
  for (int i = blockIdx.x * 256 + threadIdx.x; i < n4; i += gridDim.x * 256) {
    f32x4 v = *(const f32x4*)(in + (size_t)i * 4);
    unsigned long long u = (unsigned long long)pk2(v[0], v[1]) |
                           ((unsigned long long)pk2(v[2], v[3]) << 32);
    *(unsigned long long*)(out + (size_t)i * 4) = u;
  }
}

// ---------------- GEMM (m97 structure): C = A . BT^T + bias ----------------
template <int MODE>
__global__ __launch_bounds__(256) void k_gemm(
    const unsigned short* __restrict__ A, const unsigned short* __restrict__ BT,
    const float* __restrict__ bias, float bscale, unsigned short* __restrict__ out_a,
    unsigned short* __restrict__ out_b, float* __restrict__ out_f, int Kd) {
  __shared__ __align__(16) unsigned short As[128 * 32];
  __shared__ __align__(16) unsigned short Bs[128 * 32];
  int tid = threadIdx.x, lane = tid & 63, w = tid >> 6;
  int wm = w >> 1, wn = w & 1;

  int nwg = gridDim.x * gridDim.y;
  int bid = blockIdx.y * gridDim.x + blockIdx.x;
  int cpx = nwg >> 3;
  int sw = (bid & 7) * cpx + (bid >> 3);
  int bx = sw % gridDim.x, by = sw / gridDim.x;
  int m0 = by * 128, n0 = bx * 128;

  int srow = w * 32 + (lane >> 2);
  int scol = (lane & 3) * 8;
  const unsigned short* gA0 = A + (size_t)(m0 + srow) * Kd + scol;
  const unsigned short* gA1 = gA0 + (size_t)16 * Kd;
  const unsigned short* gB0 = BT + (size_t)(n0 + srow) * Kd + scol;
  const unsigned short* gB1 = gB0 + (size_t)16 * Kd;
  unsigned short* lA0 = As + w * 1024;
  unsigned short* lA1 = As + w * 1024 + 512;
  unsigned short* lB0 = Bs + w * 1024;
  unsigned short* lB1 = Bs + w * 1024 + 512;

  f32x4 acc[4][4];
#pragma unroll
  for (int i = 0; i < 4; ++i)
#pragma unroll
    for (int j = 0; j < 4; ++j) acc[i][j] = (f32x4){0.f, 0.f, 0.f, 0.f};

  for (int k0 = 0; k0 < Kd; k0 += 32) {
    __syncthreads();
    GL16(gA0 + k0, lA0);
    GL16(gA1 + k0, lA1);
    GL16(gB0 + k0, lB0);
    GL16(gB1 + k0, lB1);
    __syncthreads();

    s16x8 af[4], bf[4];
#pragma unroll
    for (int i = 0; i < 4; ++i) {
      af[i] = *(const s16x8*)(As + (wm * 64 + i * 16 + (lane & 15)) * 32 + (lane >> 4) * 8);
      bf[i] = *(const s16x8*)(Bs + (wn * 64 + i * 16 + (lane & 15)) * 32 + (lane >> 4) * 8);
    }
#pragma unroll
    for (int mi = 0; mi < 4; ++mi)
#pragma unroll
      for (int ni = 0; ni < 4; ++ni)
        acc[mi][ni] = __builtin_amdgcn_mfma_f32_16x16x32_bf16(af[mi], bf[ni], acc[mi][ni], 0, 0, 0);
  }

#pragma unroll
  for (int mi = 0; mi < 4; ++mi) {
#pragma unroll
    for (int ni = 0; ni < 4; ++ni) {
      int col = n0 + wn * 64 + ni * 16 + (lane & 15);
      int rbase = m0 + wm * 64 + mi * 16 + (lane >> 4) * 4;
      float bv = bias[col] * bscale;
      if (MODE == 1 && col >= H_ * DH_) {
        int c2 = col - H_ * DH_;
        int h = c2 >> 6, d = c2 & 63;
        int b = rbase >> 11, t = rbase & 2047;
        union { unsigned short h4[4]; unsigned long long u; } p;
#pragma unroll
        for (int r = 0; r < 4; ++r) p.h4[r] = f2bf(acc[mi][ni][r] + bv);
        *(unsigned long long*)(out_b + ((((size_t)b * H_ + h) * DH_ + d) * TKV_ + t)) = p.u;
      } else {
#pragma unroll
        for (int r = 0; r < 4; ++r) {
          float v = acc[mi][ni][r] + bv;
          int m = rbase + r;
          if (MODE == 0) {
            int b = m >> 11, t = m & 2047;
            int h = col >> 6, d = col & 63;
            out_a[(((size_t)b * H_ + h) * TQ_ + t) * DH_ + d] = f2bf(v);
          } else if (MODE == 1) {
            int b = m >> 11, t = m & 2047;
            int h = col >> 6, d = col & 63;
            out_a[(((size_t)b * H_ + h) * TKV_ + t) * DH_ + d] = f2bf(v);
          } else {
            out_f[(size_t)m * DM_ + col] = v;
          }
        }
      }
    }
  }
}

// ---------------- flash attention: swapped-QK^T, paired q-tiles, KV-split ----------------
// grid (8, 64) x 512 threads = 8 waves. Wave pair (w, w+4): same 32 q-rows,
// disjoint contiguous KV halves. XCD swizzle groups all 8 blocks of a head on
// one XCD for K/V L2 residency. Partial (m,l,O) merged via LDS per pass.
__global__ __launch_bounds__(512, 4) void k_attn(
    const unsigned short* __restrict__ Qb, const unsigned short* __restrict__ Kb,
    const unsigned short* __restrict__ Vtb, const unsigned char* __restrict__ mask,
    const int* __restrict__ cflag, unsigned short* __restrict__ Ob) {
  __shared__ __align__(16) unsigned short KVbuf[4][4096];  // [g*2+{K,V}][..] swizzled; merge alias 32KB
  __shared__ float bias_lds[2][64];
  __shared__ float red[8][32];
  __shared__ float red2[8][32];
  __shared__ int s_any;

  // XCD head-locality swizzle: all 8 q-blocks of a head on one XCD
  int bid = blockIdx.y * gridDim.x + blockIdx.x;
  int r8 = bid & 7, q8 = bid >> 3;
  int bh = r8 * 8 + (q8 >> 3);
  int bx = q8 & 7;

  int b = bh >> 4, h = bh & 15;
  int tid = threadIdx.x, lane = tid & 63, w = tid >> 6;
  int g = w >> 2, wq = w & 3, tg = tid & 255;
  int hi = lane >> 5, l31 = lane & 31, l7 = lane & 7;
  const unsigned short* Qp = Qb + (size_t)bh * TQ_ * DH_;
  const char* Kp = (const char*)(Kb + (size_t)bh * TKV_ * DH_);
  const char* Vp = (const char*)(Vtb + (size_t)bh * DH_ * TKV_);
  const unsigned char* mp = mask + (size_t)b * TKV_;
  int causal = cflag[0];
  char* kbase = (char*)&KVbuf[g * 2][0];
  char* vbase = (char*)&KVbuf[g * 2 + 1][0];
  float* mrg = (float*)KVbuf;

  if (tid == 0) s_any = 0;
  __syncthreads();
  {
    int any = 0;
    for (int i = tid; i < TKV_; i += 512) any |= mp[i];
    if (any) s_any = 1;
  }
  __syncthreads();
  const int has_mask = s_any;

#pragma unroll 1
  for (int pass = 0; pass < 2; ++pass) {
    int qb = (pass ? (TQ_ / 128 - 1 - bx) : bx) * 128;
    int qw = qb + wq * 32;
    int qrow = qw + l31;

    s16x8 bQ[4];
#pragma unroll
    for (int kk = 0; kk < 4; ++kk)
      bQ[kk] = *(const s16x8*)(Qp + (size_t)qrow * DH_ + kk * 16 + hi * 8);

    f32x16 accO[2];
#pragma unroll
    for (int i = 0; i < 16; ++i) { accO[0][i] = 0.f; accO[1][i] = 0.f; }
    float m_run = -INFINITY, l_run = 0.f;

    int kv_end = causal ? (qb + 128) : TKV_;
    int half = kv_end >> 1;               // multiple of 64
    int g_start = g ? half : 0;
    int nIter = half >> 6;

    for (int it = 0; it < nIter; ++it) {
      int kv0 = g_start + it * 64;
      __syncthreads();
      {  // per-group staging of K tile and V^T tile (XOR-swizzled)
        int row = tg >> 2;
        int cb0 = (tg & 3) * 16;
#pragma unroll
        for (int p = 0; p < 2; ++p) {
          int cb = cb0 + p * 64;
          int sw = cb ^ ((row & 7) << 4);
          s16x8 kvv = *(const s16x8*)(Kp + ((size_t)(kv0 + row) * 128 + cb));
          *(s16x8*)(kbase + row * 128 + sw) = kvv;
          s16x8 vvv = *(const s16x8*)(Vp + (((size_t)row * TKV_ + kv0) * 2 + cb));
          *(s16x8*)(vbase + row * 128 + sw) = vvv;
        }
        if (has_mask && tg < 64) bias_lds[g][tg] = mp[kv0 + tg] ? -1e30f : 0.0f;
      }
      __syncthreads();
      if (causal && kv0 >= qw + 32) continue;  // wave fully above diagonal

      f32x16 sT[2];
#pragma unroll
      for (int i = 0; i < 16; ++i) { sT[0][i] = 0.f; sT[1][i] = 0.f; }
#pragma unroll
      for (int s = 0; s < 2; ++s) {
#pragma unroll
        for (int kk = 0; kk < 4; ++kk) {
          s16x8 aK = *(const s16x8*)(kbase + (s * 32 + l31) * 128 +
                                     ((kk * 32 + hi * 16) ^ (l7 << 4)));
          sT[s] = __builtin_amdgcn_mfma_f32_32x32x16_bf16(aK, bQ[kk], sT[s], 0, 0, 0);
        }
      }

      int diag = causal && (kv0 + 64 > qw);
      float mx = -INFINITY;
      if (diag || has_mask) {
#pragma unroll
        for (int s = 0; s < 2; ++s)
#pragma unroll
          for (int r = 0; r < 16; ++r) {
            int kvloc = s * 32 + (r & 3) + 8 * (r >> 2) + 4 * hi;
            float sv = sT[s][r];
            if (has_mask) sv += bias_lds[g][kvloc];
            if (diag && (kv0 + kvloc) > qrow) sv = -1e30f;
            sT[s][r] = sv;
            mx = fmaxf(mx, sv);
          }
      } else {
#pragma unroll
        for (int s = 0; s < 2; ++s)
#pragma unroll
          for (int r = 0; r < 16; ++r) mx = fmaxf(mx, sT[s][r]);
      }
      mx = fmaxf(mx, __shfl_xor(mx, 32));

      if (!__all(mx - m_run <= 8.0f)) {
        float mnew = fmaxf(m_run, mx);
        float sc_o = exp2f(m_run - mnew);
        m_run = mnew;
        l_run *= sc_o;
        red[w][l31] = sc_o;
#pragma unroll
        for (int r = 0; r < 16; ++r) {
          float f = red[w][(r & 3) + 8 * (r >> 2) + 4 * hi];
          accO[0][r] *= f;
          accO[1][r] *= f;
        }
      }

      float ls = 0.f;
#pragma unroll
      for (int s = 0; s < 2; ++s)
#pragma unroll
        for (int r = 0; r < 16; ++r) {
          float p = exp2f(sT[s][r] - m_run);
          sT[s][r] = p;
          ls += p;
        }
      ls += __shfl_xor(ls, 32);
      l_run += ls;

#pragma unroll
      for (int c = 0; c < 4; ++c) {
        int s = c >> 1, kk = c & 1;
        unsigned int x0 = pk2(sT[s][8 * kk + 0], sT[s][8 * kk + 1]);
        unsigned int y0 = pk2(sT[s][8 * kk + 2], sT[s][8 * kk + 3]);
        unsigned int x1 = pk2(sT[s][8 * kk + 4], sT[s][8 * kk + 5]);
        unsigned int y1 = pk2(sT[s][8 * kk + 6], sT[s][8 * kk + 7]);
        unsigned int sx0 = __shfl_xor(x0, 32), sy0 = __shfl_xor(y0, 32);
        unsigned int sx1 = __shfl_xor(x1, 32), sy1 = __shfl_xor(y1, 32);
        union { unsigned int u[4]; s16x8 v; } pf;
        pf.u[0] = hi ? sx1 : x0;
        pf.u[1] = hi ? sy1 : y0;
        pf.u[2] = hi ? x1 : sx0;
        pf.u[3] = hi ? y1 : sy0;
#pragma unroll
        for (int dt = 0; dt < 2; ++dt) {
          s16x8 vf = *(const s16x8*)(vbase + (dt * 32 + l31) * 128 +
                                     ((c * 32 + hi * 16) ^ (l7 << 4)));
          accO[dt] = __builtin_amdgcn_mfma_f32_32x32x16_bf16(pf.v, vf, accO[dt], 0, 0, 0);
        }
      }
    }

    // ---- merge group 1 partials into group 0, then epilogue (group 0) ----
    __syncthreads();  // all waves done with KV buffers
    float* mb = mrg + (size_t)wq * 2048 + lane * 32;
    if (g == 1) {
      red[w][l31] = m_run;
      red2[w][l31] = l_run;
#pragma unroll
      for (int dt = 0; dt < 2; ++dt)
#pragma unroll
        for (int cc = 0; cc < 4; ++cc) {
          int c = dt * 4 + cc;
          f32x4 v = {accO[dt][cc * 4 + 0], accO[dt][cc * 4 + 1],
                     accO[dt][cc * 4 + 2], accO[dt][cc * 4 + 3]};
          *(f32x4*)(mb + ((c ^ l7) << 2)) = v;
        }
    }
    __syncthreads();
    if (g == 0) {
      float mB = red[w + 4][l31];
      float lB = red2[w + 4][l31];
      float mnew = fmaxf(m_run, mB);
      float sA = exp2f(m_run - mnew);
      float sB = exp2f(mB - mnew);
      l_run = l_run * sA + lB * sB;
      red[w][l31] = sA;
      red2[w][l31] = sB;
#pragma unroll
      for (int dt = 0; dt < 2; ++dt)
#pragma unroll
        for (int cc = 0; cc < 4; ++cc) {
          int c = dt * 4 + cc;
          f32x4 t = *(const f32x4*)(mb + ((c ^ l7) << 2));
#pragma unroll
          for (int j = 0; j < 4; ++j) {
            int r = cc * 4 + j;
            int R = (r & 3) + 8 * (r >> 2) + 4 * hi;
            accO[dt][r] = accO[dt][r] * red[w][R] + t[j] * red2[w][R];
          }
        }

      red[w][l31] = 1.0f / l_run;
#pragma unroll
      for (int r = 0; r < 16; ++r) {
        int R = (r & 3) + 8 * (r >> 2) + 4 * hi;
        float f = red[w][R];
        int qg = qw + R;
        size_t base = ((size_t)b * TQ_ + qg) * DM_ + h * DH_ + l31;
        Ob[base] = f2bf(accO[0][r] * f);
        Ob[base + 32] = f2bf(accO[1][r] * f);
      }
    }
  }
}

extern "C" void kernel_launch(void* const* d_in, const int* in_sizes, int n_in,
                              void* d_out, int out_size, void* d_ws, size_t ws_size,
                              hipStream_t stream) {
  const float* xq  = (const float*)d_in[0];
  const float* xkv = (const float*)d_in[1];
  const unsigned char* mask = (const unsigned char*)d_in[2];
  const float* Wq  = (const float*)d_in[3];
  const float* bq  = (const float*)d_in[4];
  const float* Wkv = (const float*)d_in[5];
  const float* bkv = (const float*)d_in[6];
  const float* Wo  = (const float*)d_in[7];
  const float* bo  = (const float*)d_in[8];
  const int* cflag = (const int*)d_in[9];
  float* out = (float*)d_out;

  char* ws = (char*)d_ws;
  unsigned short* WqT  = (unsigned short*)(ws);                       // 2 MiB
  unsigned short* WkvT = (unsigned short*)(ws + ((size_t)2 << 20));   // 4 MiB
  unsigned short* WoT  = (unsigned short*)(ws + ((size_t)6 << 20));   // 2 MiB
  unsigned short* Qb   = (unsigned short*)(ws + ((size_t)8 << 20));   // [B,H,TQ,64]
  unsigned short* Kb   = (unsigned short*)(ws + ((size_t)24 << 20));  // [B,H,TKV,64]
  unsigned short* Vb   = (unsigned short*)(ws + ((size_t)40 << 20));  // [B,H,64,TKV]
  unsigned short* Xr   = (unsigned short*)(ws + ((size_t)56 << 20));  // Aq -> Akv -> Ob
  unsigned short* Ob   = Xr;

  k_transpose_cast<<<dim3(16, 16), 256, 0, stream>>>(Wq, WqT, 1024, 1024, SC_FOLD);
  k_transpose_cast<<<dim3(32, 16), 256, 0, stream>>>(Wkv, WkvT, 1024, 2048, 1.0f);
  k_transpose_cast<<<dim3(16, 16), 256, 0, stream>>>(Wo, WoT, 1024, 1024, 1.0f);

  k_cast_bf16<<<2048, 256, 0, stream>>>(xq, Xr, B_ * TQ_ * DM_ / 4);
  k_gemm<0><<<dim3(8, 64), 256, 0, stream>>>(Xr, WqT, bq, SC_FOLD, Qb, nullptr, nullptr, 1024);

  k_cast_bf16<<<2048, 256, 0, stream>>>(xkv, Xr, B_ * TKV_ * DM_ / 4);
  k_gemm<1><<<dim3(16, 64), 256, 0, stream>>>(Xr, WkvT, bkv, 1.0f, Kb, Vb, nullptr, 1024);

  k_attn<<<dim3(8, B_ * H_), 512, 0, stream>>>(Qb, Kb, Vb, mask, cflag, Ob);

  k_gemm<2><<<dim3(8, 64), 256, 0, stream>>>(Ob, WoT, bo, 1.0f, nullptr, nullptr, out, 1024);
}